// Round 1
// baseline (136.284 us; speedup 1.0000x reference)
//
#include <hip/hip_runtime.h>
#include <math.h>

#define TT 512
#define DD 64
#define EPSF 1e-5f
#define NW 4   // waves per block

// output offsets (floats), concatenated in return order
#define O_EST  0                       // est_latent (1,2,512,64)   = 65536
#define O_QIJ  (2*TT*DD)               // Q_ij (1,512,512,64)       = 16777216
#define O_ZHAT (O_QIJ + TT*TT*DD)      // Zhat (1,2,512,512,64)     = 33554432
#define O_LH   (O_ZHAT + 2*TT*TT*DD)   // lambda_h (2,64)
#define O_ME   (O_LH + 2*DD)           // mat_exp (1,2,64)

// ---------------- Q/K projection: Q[c,t,o] = sum_i Z[c,t,i]*W[o,i] + b[o] ----
__global__ __launch_bounds__(128) void afa_proj_kernel(
    const float* __restrict__ Zq, const float* __restrict__ Zk,
    const float* __restrict__ Wq_w, const float* __restrict__ Wq_b,
    const float* __restrict__ Wk_w, const float* __restrict__ Wk_b,
    float* __restrict__ Qbuf, float* __restrict__ Kbuf)
{
    int b = blockIdx.x;          // 0 .. 2*TT-1
    int c = b / TT, t = b % TT;
    __shared__ float zq[DD], zk[DD];
    int tid = threadIdx.x;
    if (tid < DD) zq[tid] = Zq[(c*TT + t)*DD + tid];
    else          zk[tid-DD] = Zk[(c*TT + t)*DD + (tid-DD)];
    __syncthreads();
    int o = tid & 63;
    if (tid < 64) {
        float acc = Wq_b[o];
        #pragma unroll 16
        for (int i = 0; i < DD; ++i) acc = fmaf(zq[i], Wq_w[o*DD + i], acc);
        Qbuf[(c*TT + t)*DD + o] = acc;
    } else {
        float acc = Wk_b[o];
        #pragma unroll 16
        for (int i = 0; i < DD; ++i) acc = fmaf(zk[i], Wk_w[o*DD + i], acc);
        Kbuf[(c*TT + t)*DD + o] = acc;
    }
}

// ---------------- tiny outputs: lambda_h, mat_exp ---------------------------
__global__ __launch_bounds__(64) void afa_tail_kernel(
    const float* __restrict__ l1, const float* __restrict__ t_all,
    float* __restrict__ out)
{
    int d = threadIdx.x;              // 0..63
    int h = d & 31;
    float a  = -fabsf(l1[h]);
    float bb = (d < 32) ? l1[32 + h] : -l1[32 + h];
    out[O_LH + d]      = a;
    out[O_LH + DD + d] = bb;
    float dT = t_all[TT] - t_all[TT-1];
    float me = __expf(a * dT);
    out[O_ME + d]      = me * __cosf(bb * dT);
    out[O_ME + DD + d] = me * __sinf(bb * dT);
}

// ---------------- main: per-row scores, softmax, Q_ij/Zhat/est_latent -------
__global__ __launch_bounds__(256) void afa_main_kernel(
    const float* __restrict__ Zv,
    const float* __restrict__ t_all,
    const float* __restrict__ l1,
    const float* __restrict__ lOm_, const float* __restrict__ lGa_,
    const float* __restrict__ nf,  const float* __restrict__ tau_,
    const float* __restrict__ nu_, const float* __restrict__ etap,
    const float* __restrict__ lC,
    const float* __restrict__ Qbuf, const float* __restrict__ Kbuf,
    float* __restrict__ out)
{
    int bid = blockIdx.x;
    // pair light/heavy rows so dispatch order spreads work evenly
    int i = (bid & 1) ? (TT - 1 - (bid >> 1)) : (bid >> 1);
    int tid = threadIdx.x;
    int w = tid >> 6;     // wave 0..3
    int d = tid & 63;     // lane = feature dim

    __shared__ float t_lds[TT];
    __shared__ float redA[NW][DD];
    __shared__ float redB[NW][DD];

    for (int k = tid; k < TT; k += 256) t_lds[k] = t_all[k];

    // per-lane constants
    int h = d & 31;
    float a  = -fabsf(l1[h]);
    float bc = (d < 32) ? l1[32 + h] : -l1[32 + h];
    float lOm = fabsf(lOm_[d]);
    float lGa = fabsf(lGa_[d]) + EPSF;
    float c1  = lC[d] * lOm / (-2.0f * a + EPSF);
    float noise = fabsf(nf[0]);
    float tau_a = fabsf(tau_[0]);
    float nu_a  = fabsf(nu_[0]);
    float ti = t_all[i];
    float Qr = Qbuf[(0*TT + i)*DD + d];
    float Qi = Qbuf[(1*TT + i)*DD + d];
    const float* __restrict__ KrB = Kbuf;
    const float* __restrict__ KiB = Kbuf + TT*DD;
    const float* __restrict__ VrB = Zv;
    const float* __restrict__ ViB = Zv + TT*DD;

    __syncthreads();

    // ---- Phase 1: online softmax stats (per lane d, over this wave's j's)
    float m = -INFINITY, s = 0.0f;
    for (int j = w; j <= i; j += NW) {
        float dt = ti - t_lds[j];
        float e  = __expf(a * dt);
        float ang = bc * dt;
        float cs = __cosf(ang), sn = __sinf(ang);
        float kr = KrB[j*DD + d], ki = KiB[j*DD + d];
        float Rr = Qr - e * (cs*kr - sn*ki);
        float Ri = Qi - e * (sn*kr + cs*ki);
        float Vij = c1 * (1.0f - e*e);
        float mah = (Rr*Rr + Ri*Ri) / (Vij + lGa);
        float sum = mah;
        sum += __shfl_xor(sum, 1);
        sum += __shfl_xor(sum, 2);
        sum += __shfl_xor(sum, 4);
        sum += __shfl_xor(sum, 8);
        sum += __shfl_xor(sum, 16);
        sum += __shfl_xor(sum, 32);
        float base = Vij * (noise + nu_a * sum);
        float sc = -tau_a * __logf(base + EPSF);
        float nm = fmaxf(m, sc);
        s = s * __expf(m - nm) + __expf(sc - nm);
        m = nm;
    }
    redA[w][d] = m;
    redB[w][d] = s;
    __syncthreads();
    float M = redA[0][d];
    #pragma unroll
    for (int ww = 1; ww < NW; ++ww) M = fmaxf(M, redA[ww][d]);
    float S = 0.0f;
    #pragma unroll
    for (int ww = 0; ww < NW; ++ww) S += redB[ww][d] * __expf(redA[ww][d] - M);
    float invS = 1.0f / S;

    // ---- Phase 2: recompute, write Q_ij & Zhat, accumulate est_v_avg
    float accr = 0.0f, acci = 0.0f;
    float* __restrict__ Qout  = out + O_QIJ  + (size_t)i*TT*DD;
    float* __restrict__ Z0out = out + O_ZHAT + (size_t)i*TT*DD;
    float* __restrict__ Z1out = out + O_ZHAT + (size_t)TT*TT*DD + (size_t)i*TT*DD;
    for (int j = w; j <= i; j += NW) {
        float dt = ti - t_lds[j];
        float e  = __expf(a * dt);
        float ang = bc * dt;
        float cs = __cosf(ang), sn = __sinf(ang);
        float kr = KrB[j*DD + d], ki = KiB[j*DD + d];
        float vr = VrB[j*DD + d], vi = ViB[j*DD + d];
        float Rr = Qr - e * (cs*kr - sn*ki);
        float Ri = Qi - e * (sn*kr + cs*ki);
        float Vij = c1 * (1.0f - e*e);
        float mah = (Rr*Rr + Ri*Ri) / (Vij + lGa);
        float sum = mah;
        sum += __shfl_xor(sum, 1);
        sum += __shfl_xor(sum, 2);
        sum += __shfl_xor(sum, 4);
        sum += __shfl_xor(sum, 8);
        sum += __shfl_xor(sum, 16);
        sum += __shfl_xor(sum, 32);
        float base = Vij * (noise + nu_a * sum);
        float sc = -tau_a * __logf(base + EPSF);
        float q = __expf(sc - M) * invS;
        float Zr = e * (cs*vr - sn*vi);
        float Zi = e * (sn*vr + cs*vi);
        Qout [j*DD + d] = q;
        Z0out[j*DD + d] = Zr;
        Z1out[j*DD + d] = Zi;
        accr = fmaf(q, Zr, accr);
        acci = fmaf(q, Zi, acci);
    }
    __syncthreads();               // everyone done reading redA/redB
    redA[w][d] = accr;
    redB[w][d] = acci;
    __syncthreads();
    if (tid < 64) {
        float ar = 0.0f, ai = 0.0f;
        #pragma unroll
        for (int ww = 0; ww < NW; ++ww) { ar += redA[ww][d]; ai += redB[ww][d]; }
        float eta = 1.0f / (1.0f + __expf(-etap[d]));
        float vr = VrB[i*DD + d], vi = ViB[i*DD + d];
        out[O_EST + (0*TT + i)*DD + d] = (1.0f - eta)*vr + eta*ar;
        out[O_EST + (1*TT + i)*DD + d] = (1.0f - eta)*vi + eta*ai;
    }

    // ---- zero-fill the non-causal (j>i) parts of Q_ij and Zhat
    int nz = (TT - 1 - i) * DD / 4;    // float4 count per region
    float4 z4 = make_float4(0.f, 0.f, 0.f, 0.f);
    float4* q4  = (float4*)(Qout  + (i+1)*DD);
    float4* z04 = (float4*)(Z0out + (i+1)*DD);
    float4* z14 = (float4*)(Z1out + (i+1)*DD);
    for (int k = tid; k < nz; k += 256) {
        q4[k] = z4; z04[k] = z4; z14[k] = z4;
    }
}

extern "C" void kernel_launch(void* const* d_in, const int* in_sizes, int n_in,
                              void* d_out, int out_size, void* d_ws, size_t ws_size,
                              hipStream_t stream) {
    const float* Zq    = (const float*)d_in[0];
    const float* Zk    = (const float*)d_in[1];
    const float* Zv    = (const float*)d_in[2];
    const float* t_all = (const float*)d_in[3];
    const float* Wq_w  = (const float*)d_in[4];
    const float* Wq_b  = (const float*)d_in[5];
    const float* Wk_w  = (const float*)d_in[6];
    const float* Wk_b  = (const float*)d_in[7];
    const float* l1    = (const float*)d_in[8];
    const float* lOm   = (const float*)d_in[9];
    const float* lGa   = (const float*)d_in[10];
    const float* nf    = (const float*)d_in[11];
    const float* tau   = (const float*)d_in[12];
    const float* nu    = (const float*)d_in[13];
    const float* etap  = (const float*)d_in[14];
    const float* lC    = (const float*)d_in[15];
    float* out = (float*)d_out;

    float* Qbuf = (float*)d_ws;              // 2*512*64 floats
    float* Kbuf = Qbuf + 2*TT*DD;            // 2*512*64 floats

    afa_proj_kernel<<<2*TT, 128, 0, stream>>>(Zq, Zk, Wq_w, Wq_b, Wk_w, Wk_b,
                                              Qbuf, Kbuf);
    afa_tail_kernel<<<1, 64, 0, stream>>>(l1, t_all, out);
    afa_main_kernel<<<TT, 256, 0, stream>>>(Zv, t_all, l1, lOm, lGa, nf, tau,
                                            nu, etap, lC, Qbuf, Kbuf, out);
}

// Round 3
// 78.249 us; speedup vs baseline: 1.7417x; 1.7417x over previous
//
#include <hip/hip_runtime.h>
#include <math.h>

#define TT 512
#define DD 64
#define EPSF 1e-5f
#define NEG_BIG (-1e30f)

// output offsets (floats), concatenated in return order
#define O_EST  0                       // est_latent (1,2,512,64)
#define O_QIJ  (2*TT*DD)               // Q_ij (1,512,512,64)
#define O_ZHAT (O_QIJ + TT*TT*DD)      // Zhat (1,2,512,512,64)
#define O_LH   (O_ZHAT + 2*TT*TT*DD)   // lambda_h (2,64)
#define O_ME   (O_LH + 2*DD)           // mat_exp (1,2,64)

// ws layout (floats)
#define W_QBUF 0
#define W_KBUF (W_QBUF + 2*TT*DD)
#define W_SIJ  (W_KBUF + 2*TT*DD)          // [i*TT+j], causal only
#define W_M    (W_SIJ + TT*TT)             // [(i*4+ch)*64+d] partial max
#define W_S    (W_M + TT*4*DD)
#define W_AR   (W_S + TT*4*DD)
#define W_AI   (W_AR + TT*4*DD)
#define W_MF   (W_AI + TT*4*DD)            // final M per (i,d)
#define W_IS   (W_MF + TT*DD)              // final 1/S per (i,d)

// ---------------- Q/K projection ----------------------------------------
__global__ __launch_bounds__(128) void afa_proj_kernel(
    const float* __restrict__ Zq, const float* __restrict__ Zk,
    const float* __restrict__ Wq_w, const float* __restrict__ Wq_b,
    const float* __restrict__ Wk_w, const float* __restrict__ Wk_b,
    float* __restrict__ Qbuf, float* __restrict__ Kbuf)
{
    int b = blockIdx.x;          // 0 .. 2*TT-1
    int c = b / TT, t = b % TT;
    __shared__ float zq[DD], zk[DD];
    int tid = threadIdx.x;
    if (tid < DD) zq[tid] = Zq[(c*TT + t)*DD + tid];
    else          zk[tid-DD] = Zk[(c*TT + t)*DD + (tid-DD)];
    __syncthreads();
    int o = tid & 63;
    if (tid < 64) {
        float acc = Wq_b[o];
        #pragma unroll 16
        for (int i = 0; i < DD; ++i) acc = fmaf(zq[i], Wq_w[o*DD + i], acc);
        Qbuf[(c*TT + t)*DD + o] = acc;
    } else {
        float acc = Wk_b[o];
        #pragma unroll 16
        for (int i = 0; i < DD; ++i) acc = fmaf(zk[i], Wk_w[o*DD + i], acc);
        Kbuf[(c*TT + t)*DD + o] = acc;
    }
}

// ---------------- tiny outputs: lambda_h, mat_exp ------------------------
__global__ __launch_bounds__(64) void afa_tail_kernel(
    const float* __restrict__ l1, const float* __restrict__ t_all,
    float* __restrict__ out)
{
    int d = threadIdx.x;
    int h = d & 31;
    float a  = -fabsf(l1[h]);
    float bb = (d < 32) ? l1[32 + h] : -l1[32 + h];
    out[O_LH + d]      = a;
    out[O_LH + DD + d] = bb;
    float dT = t_all[TT] - t_all[TT-1];
    float me = __expf(a * dT);
    out[O_ME + d]      = me * __cosf(bb * dT);
    out[O_ME + DD + d] = me * __sinf(bb * dT);
}

// ---------------- stats: S_ij, online softmax partials --------------------
__global__ __launch_bounds__(256) void afa_stats_kernel(
    const float* __restrict__ Zv, const float* __restrict__ t_all,
    const float* __restrict__ l1,
    const float* __restrict__ lOm_, const float* __restrict__ lGa_,
    const float* __restrict__ nf,  const float* __restrict__ tau_,
    const float* __restrict__ nu_, const float* __restrict__ lC,
    float* __restrict__ ws)
{
    const float* Qbuf = ws + W_QBUF;
    const float* Kbuf = ws + W_KBUF;
    float* Sij = ws + W_SIJ;

    int bid = blockIdx.x;            // 2048 = 512 rows * 4 chunks
    int ch = bid & 3;
    int r  = bid >> 2;
    int i  = (r & 1) ? (TT - 1 - (r >> 1)) : (r >> 1);
    int tid = threadIdx.x;
    int w = tid >> 6, d = tid & 63;

    __shared__ float t_lds[TT];
    __shared__ float rm[4][DD], rs[4][DD], rr[4][DD], ri_[4][DD];
    for (int k = tid; k < TT; k += 256) t_lds[k] = t_all[k];

    int h = d & 31;
    float a  = -fabsf(l1[h]);
    float bc = (d < 32) ? l1[32 + h] : -l1[32 + h];
    float lGa = fabsf(lGa_[d]) + EPSF;
    float c1  = lC[d] * fabsf(lOm_[d]) / (-2.0f * a + EPSF);
    float noise = fabsf(nf[0]);
    float tau_a = fabsf(tau_[0]);
    float nu_a  = fabsf(nu_[0]);
    float ti = t_all[i];
    float Qr = Qbuf[i*DD + d];
    float Qi = Qbuf[TT*DD + i*DD + d];
    const float* __restrict__ KrB = Kbuf;
    const float* __restrict__ KiB = Kbuf + TT*DD;
    const float* __restrict__ VrB = Zv;
    const float* __restrict__ ViB = Zv + TT*DD;

    __syncthreads();

    // finite sentinel: empty chunks must NOT produce inf-inf = NaN
    float m = NEG_BIG, s = 0.0f, ar = 0.0f, ai = 0.0f;
    for (int j = ch*4 + w; j <= i; j += 16) {
        float dt = ti - t_lds[j];
        float e  = __expf(a * dt);
        float ang = bc * dt;
        float cs = __cosf(ang), sn = __sinf(ang);
        float kr = KrB[j*DD + d], ki = KiB[j*DD + d];
        float vr = VrB[j*DD + d], vi = ViB[j*DD + d];
        float Rr = Qr - e * (cs*kr - sn*ki);
        float Ri = Qi - e * (sn*kr + cs*ki);
        float Vij = c1 * (1.0f - e*e);
        float mah = (Rr*Rr + Ri*Ri) / (Vij + lGa);
        float sum = mah;
        sum += __shfl_xor(sum, 1);
        sum += __shfl_xor(sum, 2);
        sum += __shfl_xor(sum, 4);
        sum += __shfl_xor(sum, 8);
        sum += __shfl_xor(sum, 16);
        sum += __shfl_xor(sum, 32);
        if (d == 0) Sij[i*TT + j] = sum;
        float base = Vij * (noise + nu_a * sum);
        float sc = -tau_a * __logf(base + EPSF);
        float Zr = e * (cs*vr - sn*vi);
        float Zi = e * (sn*vr + cs*vi);
        float nm = fmaxf(m, sc);
        float f = __expf(m - nm);
        float p = __expf(sc - nm);
        s  = s*f + p;
        ar = ar*f + p*Zr;
        ai = ai*f + p*Zi;
        m  = nm;
    }
    rm[w][d] = m; rs[w][d] = s; rr[w][d] = ar; ri_[w][d] = ai;
    __syncthreads();
    if (tid < 64) {
        float M = rm[0][d];
        #pragma unroll
        for (int ww = 1; ww < 4; ++ww) M = fmaxf(M, rm[ww][d]);
        float S = 0.0f, AR = 0.0f, AI = 0.0f;
        #pragma unroll
        for (int ww = 0; ww < 4; ++ww) {
            float f = __expf(rm[ww][d] - M);   // finite-finite: no NaN
            S  += rs[ww][d]*f;
            AR += rr[ww][d]*f;
            AI += ri_[ww][d]*f;
        }
        int o = (i*4 + ch)*DD + d;
        ws[W_M  + o] = M;
        ws[W_S  + o] = S;
        ws[W_AR + o] = AR;
        ws[W_AI + o] = AI;
    }
}

// ---------------- combine partials -> M, 1/S, est_latent ------------------
__global__ __launch_bounds__(256) void afa_combine_kernel(
    const float* __restrict__ Zv, const float* __restrict__ etap,
    float* __restrict__ ws, float* __restrict__ out)
{
    int idx = blockIdx.x*256 + threadIdx.x;   // 0..32767 = i*64+d
    int i = idx >> 6, d = idx & 63;
    float M = NEG_BIG;
    #pragma unroll
    for (int c = 0; c < 4; ++c) M = fmaxf(M, ws[W_M + (i*4 + c)*DD + d]);
    float S = 0.0f, AR = 0.0f, AI = 0.0f;
    #pragma unroll
    for (int c = 0; c < 4; ++c) {
        int o = (i*4 + c)*DD + d;
        float f = __expf(ws[W_M + o] - M);     // empty chunk: exp(-huge)=0
        S  += ws[W_S  + o]*f;
        AR += ws[W_AR + o]*f;
        AI += ws[W_AI + o]*f;
    }
    float inv = 1.0f / S;
    ws[W_MF + idx] = M;
    ws[W_IS + idx] = inv;
    float eta = 1.0f / (1.0f + __expf(-etap[d]));
    float vr = Zv[i*DD + d], vi = Zv[TT*DD + i*DD + d];
    out[O_EST + idx]         = (1.0f - eta)*vr + eta*AR*inv;
    out[O_EST + TT*DD + idx] = (1.0f - eta)*vi + eta*AI*inv;
}

// ---------------- writer: Q_ij, Zhat (the 200 MB stream) ------------------
__global__ __launch_bounds__(256) void afa_write_kernel(
    const float* __restrict__ Zv, const float* __restrict__ t_all,
    const float* __restrict__ l1, const float* __restrict__ lOm_,
    const float* __restrict__ nf, const float* __restrict__ tau_,
    const float* __restrict__ nu_, const float* __restrict__ lC,
    const float* __restrict__ ws, float* __restrict__ out)
{
    int bid = blockIdx.x;            // 512*64 = 32768
    int i  = bid >> 6;
    int jt = bid & 63;               // 8 j's per block
    int tid = threadIdx.x;
    int w = tid >> 6, d = tid & 63;

    float* __restrict__ Qout  = out + O_QIJ  + (size_t)i*TT*DD;
    float* __restrict__ Z0out = out + O_ZHAT + (size_t)i*TT*DD;
    float* __restrict__ Z1out = out + O_ZHAT + (size_t)TT*TT*DD + (size_t)i*TT*DD;

    int j0 = jt*8;
    if (j0 > i) {                    // fully non-causal: float4 zero-fill
        if (tid < 128) {
            float4 z = make_float4(0.f,0.f,0.f,0.f);
            ((float4*)(Qout  + j0*DD))[tid] = z;
            ((float4*)(Z0out + j0*DD))[tid] = z;
            ((float4*)(Z1out + j0*DD))[tid] = z;
        }
        return;
    }

    int h = d & 31;
    float a  = -fabsf(l1[h]);
    float bc = (d < 32) ? l1[32 + h] : -l1[32 + h];
    float c1 = lC[d] * fabsf(lOm_[d]) / (-2.0f * a + EPSF);
    float noise = fabsf(nf[0]);
    float tau_a = fabsf(tau_[0]);
    float nu_a  = fabsf(nu_[0]);
    float ti = t_all[i];
    float M   = ws[W_MF + i*DD + d];
    float inv = ws[W_IS + i*DD + d];
    const float* __restrict__ VrB = Zv;
    const float* __restrict__ ViB = Zv + TT*DD;

    #pragma unroll
    for (int k = 0; k < 2; ++k) {
        int j = j0 + w + 4*k;
        if (j <= i) {
            float dt = ti - t_all[j];
            float e  = __expf(a * dt);
            float ang = bc * dt;
            float cs = __cosf(ang), sn = __sinf(ang);
            float vr = VrB[j*DD + d], vi = ViB[j*DD + d];
            float Vij = c1 * (1.0f - e*e);
            float Sj = ws[W_SIJ + i*TT + j];
            float base = Vij * (noise + nu_a * Sj);
            float sc = -tau_a * __logf(base + EPSF);
            float q = __expf(sc - M) * inv;
            float Zr = e * (cs*vr - sn*vi);
            float Zi = e * (sn*vr + cs*vi);
            Qout [j*DD + d] = q;
            Z0out[j*DD + d] = Zr;
            Z1out[j*DD + d] = Zi;
        } else {
            Qout [j*DD + d] = 0.0f;
            Z0out[j*DD + d] = 0.0f;
            Z1out[j*DD + d] = 0.0f;
        }
    }
}

extern "C" void kernel_launch(void* const* d_in, const int* in_sizes, int n_in,
                              void* d_out, int out_size, void* d_ws, size_t ws_size,
                              hipStream_t stream) {
    const float* Zq    = (const float*)d_in[0];
    const float* Zk    = (const float*)d_in[1];
    const float* Zv    = (const float*)d_in[2];
    const float* t_all = (const float*)d_in[3];
    const float* Wq_w  = (const float*)d_in[4];
    const float* Wq_b  = (const float*)d_in[5];
    const float* Wk_w  = (const float*)d_in[6];
    const float* Wk_b  = (const float*)d_in[7];
    const float* l1    = (const float*)d_in[8];
    const float* lOm   = (const float*)d_in[9];
    const float* lGa   = (const float*)d_in[10];
    const float* nf    = (const float*)d_in[11];
    const float* tau   = (const float*)d_in[12];
    const float* nu    = (const float*)d_in[13];
    const float* etap  = (const float*)d_in[14];
    const float* lC    = (const float*)d_in[15];
    float* out = (float*)d_out;
    float* ws  = (float*)d_ws;

    afa_proj_kernel<<<2*TT, 128, 0, stream>>>(Zq, Zk, Wq_w, Wq_b, Wk_w, Wk_b,
                                              ws + W_QBUF, ws + W_KBUF);
    afa_tail_kernel<<<1, 64, 0, stream>>>(l1, t_all, out);
    afa_stats_kernel<<<TT*4, 256, 0, stream>>>(Zv, t_all, l1, lOm, lGa, nf,
                                               tau, nu, lC, ws);
    afa_combine_kernel<<<TT*DD/256, 256, 0, stream>>>(Zv, etap, ws, out);
    afa_write_kernel<<<TT*64, 256, 0, stream>>>(Zv, t_all, l1, lOm, nf, tau,
                                                nu, lC, ws, out);
}

// Round 4
// 72.066 us; speedup vs baseline: 1.8911x; 1.0858x over previous
//
#include <hip/hip_runtime.h>
#include <math.h>

#define TT 512
#define DD 64
#define EPSF 1e-5f

// output offsets (floats), concatenated in return order
#define O_EST  0                       // est_latent (1,2,512,64)
#define O_QIJ  (2*TT*DD)               // Q_ij (1,512,512,64)
#define O_ZHAT (O_QIJ + TT*TT*DD)      // Zhat (1,2,512,512,64)
#define O_LH   (O_ZHAT + 2*TT*TT*DD)   // lambda_h (2,64)
#define O_ME   (O_LH + 2*DD)           // mat_exp (1,2,64)

// ws layout (floats)
#define W_QBUF 0
#define W_KBUF (W_QBUF + 2*TT*DD)
#define W_SIJ  (W_KBUF + 2*TT*DD)          // [i*TT+j], causal only
#define W_S    (W_SIJ + TT*TT)             // [(i*4+ch)*64+d] partial sum (M=0 ref)
#define W_AR   (W_S + TT*4*DD)
#define W_AI   (W_AR + TT*4*DD)
#define W_IS   (W_AI + TT*4*DD)            // final 1/S per (i,d)
#define W_CA   (W_IS + TT*DD)              // a[d]
#define W_CB   (W_CA + DD)                 // bc[d]
#define W_CC   (W_CB + DD)                 // c1[d]

// ---------------- Q/K projection ----------------------------------------
__global__ __launch_bounds__(128) void afa_proj_kernel(
    const float* __restrict__ Zq, const float* __restrict__ Zk,
    const float* __restrict__ Wq_w, const float* __restrict__ Wq_b,
    const float* __restrict__ Wk_w, const float* __restrict__ Wk_b,
    float* __restrict__ Qbuf, float* __restrict__ Kbuf)
{
    int b = blockIdx.x;          // 0 .. 2*TT-1
    int c = b / TT, t = b % TT;
    __shared__ float zq[DD], zk[DD];
    int tid = threadIdx.x;
    if (tid < DD) zq[tid] = Zq[(c*TT + t)*DD + tid];
    else          zk[tid-DD] = Zk[(c*TT + t)*DD + (tid-DD)];
    __syncthreads();
    int o = tid & 63;
    const float* __restrict__ W  = (tid < 64) ? Wq_w : Wk_w;
    const float* __restrict__ bs = (tid < 64) ? Wq_b : Wk_b;
    const float* __restrict__ z  = (tid < 64) ? zq : zk;
    float* __restrict__ dst      = (tid < 64) ? Qbuf : Kbuf;
    float acc = bs[o];
    #pragma unroll
    for (int i4 = 0; i4 < 16; ++i4) {
        float4 w4 = *(const float4*)&W[o*DD + i4*4];
        acc = fmaf(z[i4*4+0], w4.x, acc);
        acc = fmaf(z[i4*4+1], w4.y, acc);
        acc = fmaf(z[i4*4+2], w4.z, acc);
        acc = fmaf(z[i4*4+3], w4.w, acc);
    }
    dst[(c*TT + t)*DD + o] = acc;
}

// ---------------- tiny outputs + per-d constant tables --------------------
__global__ __launch_bounds__(64) void afa_tail_kernel(
    const float* __restrict__ l1, const float* __restrict__ t_all,
    const float* __restrict__ lOm_, const float* __restrict__ lC,
    float* __restrict__ ws, float* __restrict__ out)
{
    int d = threadIdx.x;
    int h = d & 31;
    float a  = -fabsf(l1[h]);
    float bb = (d < 32) ? l1[32 + h] : -l1[32 + h];
    out[O_LH + d]      = a;
    out[O_LH + DD + d] = bb;
    float dT = t_all[TT] - t_all[TT-1];
    float me = __expf(a * dT);
    out[O_ME + d]      = me * __cosf(bb * dT);
    out[O_ME + DD + d] = me * __sinf(bb * dT);
    ws[W_CA + d] = a;
    ws[W_CB + d] = bb;
    ws[W_CC + d] = lC[d] * fabsf(lOm_[d]) / (-2.0f * a + EPSF);
}

// ---------------- stats: S_ij, fixed-ref (M=0) softmax partials -----------
__global__ __launch_bounds__(256) void afa_stats_kernel(
    const float* __restrict__ Zv, const float* __restrict__ t_all,
    const float* __restrict__ l1,
    const float* __restrict__ lOm_, const float* __restrict__ lGa_,
    const float* __restrict__ nf,  const float* __restrict__ tau_,
    const float* __restrict__ nu_, const float* __restrict__ lC,
    float* __restrict__ ws)
{
    const float* Qbuf = ws + W_QBUF;
    const float* Kbuf = ws + W_KBUF;
    float* Sij = ws + W_SIJ;

    int bid = blockIdx.x;            // 2048 = 512 rows * 4 chunks
    int ch = bid & 3;
    int r  = bid >> 2;
    int i  = (r & 1) ? (TT - 1 - (r >> 1)) : (r >> 1);
    int tid = threadIdx.x;
    int w = tid >> 6, d = tid & 63;

    __shared__ float t_lds[TT];
    __shared__ float rs[4][DD], rr[4][DD], ri_[4][DD];
    for (int k = tid; k < TT; k += 256) t_lds[k] = t_all[k];

    int h = d & 31;
    float a  = -fabsf(l1[h]);
    float bc = (d < 32) ? l1[32 + h] : -l1[32 + h];
    float lGa = fabsf(lGa_[d]) + EPSF;
    float c1  = lC[d] * fabsf(lOm_[d]) / (-2.0f * a + EPSF);
    float noise = fabsf(nf[0]);
    float tau_a = fabsf(tau_[0]);
    float nu_a  = fabsf(nu_[0]);
    float ti = t_all[i];
    float Qr = Qbuf[i*DD + d];
    float Qi = Qbuf[TT*DD + i*DD + d];
    const float* __restrict__ KrB = Kbuf;
    const float* __restrict__ KiB = Kbuf + TT*DD;
    const float* __restrict__ VrB = Zv;
    const float* __restrict__ ViB = Zv + TT*DD;

    __syncthreads();

    // fixed reference max (M=0): scores are bounded (|sc| <~ 14*tau),
    // so exp(sc) is safe in fp32 and iterations carry only 3 adds.
    float s = 0.0f, ar = 0.0f, ai = 0.0f;
    for (int j = ch*4 + w; j <= i; j += 16) {
        float dt = ti - t_lds[j];
        float e  = __expf(a * dt);
        float ang = bc * dt;
        float cs = __cosf(ang), sn = __sinf(ang);
        float kr = KrB[j*DD + d], ki = KiB[j*DD + d];
        float vr = VrB[j*DD + d], vi = ViB[j*DD + d];
        float Rr = Qr - e * (cs*kr - sn*ki);
        float Ri = Qi - e * (sn*kr + cs*ki);
        float Vij = c1 * (1.0f - e*e);
        float mah = (Rr*Rr + Ri*Ri) / (Vij + lGa);
        float sum = mah;
        sum += __shfl_xor(sum, 1);
        sum += __shfl_xor(sum, 2);
        sum += __shfl_xor(sum, 4);
        sum += __shfl_xor(sum, 8);
        sum += __shfl_xor(sum, 16);
        sum += __shfl_xor(sum, 32);
        if (d == 0) Sij[i*TT + j] = sum;
        float base = Vij * (noise + nu_a * sum);
        float sc = -tau_a * __logf(base + EPSF);
        float p  = __expf(sc);
        float Zr = e * (cs*vr - sn*vi);
        float Zi = e * (sn*vr + cs*vi);
        s  += p;
        ar = fmaf(p, Zr, ar);
        ai = fmaf(p, Zi, ai);
    }
    rs[w][d] = s; rr[w][d] = ar; ri_[w][d] = ai;
    __syncthreads();
    if (tid < 64) {
        float S = 0.0f, AR = 0.0f, AI = 0.0f;
        #pragma unroll
        for (int ww = 0; ww < 4; ++ww) {
            S  += rs[ww][d];
            AR += rr[ww][d];
            AI += ri_[ww][d];
        }
        int o = (i*4 + ch)*DD + d;
        ws[W_S  + o] = S;
        ws[W_AR + o] = AR;
        ws[W_AI + o] = AI;
    }
}

// ---------------- combine partials -> 1/S, est_latent ---------------------
__global__ __launch_bounds__(256) void afa_combine_kernel(
    const float* __restrict__ Zv, const float* __restrict__ etap,
    float* __restrict__ ws, float* __restrict__ out)
{
    int idx = blockIdx.x*256 + threadIdx.x;   // 0..32767 = i*64+d
    int i = idx >> 6, d = idx & 63;
    float S = 0.0f, AR = 0.0f, AI = 0.0f;
    #pragma unroll
    for (int c = 0; c < 4; ++c) {
        int o = (i*4 + c)*DD + d;
        S  += ws[W_S  + o];
        AR += ws[W_AR + o];
        AI += ws[W_AI + o];
    }
    float inv = 1.0f / S;
    ws[W_IS + idx] = inv;
    float eta = 1.0f / (1.0f + __expf(-etap[d]));
    float vr = Zv[i*DD + d], vi = Zv[TT*DD + i*DD + d];
    out[O_EST + idx]         = (1.0f - eta)*vr + eta*AR*inv;
    out[O_EST + TT*DD + idx] = (1.0f - eta)*vi + eta*AI*inv;
}

// ---------------- writer: Q_ij, Zhat (the 200 MB stream), float4 ---------
__global__ __launch_bounds__(256) void afa_write_kernel(
    const float* __restrict__ Zv, const float* __restrict__ t_all,
    const float* __restrict__ nf, const float* __restrict__ tau_,
    const float* __restrict__ nu_,
    const float* __restrict__ ws, float* __restrict__ out)
{
    int bid = blockIdx.x;            // 512*32 = 16384
    int i  = bid >> 5;
    int jt = bid & 31;               // 16 j's per block
    int tid = threadIdx.x;
    int jl = tid >> 4;               // 0..15
    int d0 = (tid & 15) * 4;         // 0,4,...,60
    int j  = jt*16 + jl;

    float* __restrict__ Qout  = out + O_QIJ  + (size_t)i*TT*DD;
    float* __restrict__ Z0out = out + O_ZHAT + (size_t)i*TT*DD;
    float* __restrict__ Z1out = out + O_ZHAT + (size_t)TT*TT*DD + (size_t)i*TT*DD;

    float4 z4 = make_float4(0.f, 0.f, 0.f, 0.f);
    if (jt*16 > i) {                 // fully non-causal tile: zero-fill
        *(float4*)&Qout [j*DD + d0] = z4;
        *(float4*)&Z0out[j*DD + d0] = z4;
        *(float4*)&Z1out[j*DD + d0] = z4;
        return;
    }

    if (j > i) {
        *(float4*)&Qout [j*DD + d0] = z4;
        *(float4*)&Z0out[j*DD + d0] = z4;
        *(float4*)&Z1out[j*DD + d0] = z4;
        return;
    }

    float noise = fabsf(nf[0]);
    float tau_a = fabsf(tau_[0]);
    float nu_a  = fabsf(nu_[0]);
    float4 A4   = *(const float4*)&ws[W_CA + d0];
    float4 B4   = *(const float4*)&ws[W_CB + d0];
    float4 C4   = *(const float4*)&ws[W_CC + d0];
    float4 inv4 = *(const float4*)&ws[W_IS + i*DD + d0];
    float dt = t_all[i] - t_all[j];
    float Sj = ws[W_SIJ + i*TT + j];
    float w1 = noise + nu_a * Sj;
    float4 Vr4 = *(const float4*)&Zv[j*DD + d0];
    float4 Vi4 = *(const float4*)&Zv[TT*DD + j*DD + d0];

    float4 q4, o0, o1;
    {
        const float* A = (const float*)&A4;
        const float* B = (const float*)&B4;
        const float* C = (const float*)&C4;
        const float* IV = (const float*)&inv4;
        const float* VR = (const float*)&Vr4;
        const float* VI = (const float*)&Vi4;
        float* Q = (float*)&q4;
        float* P0 = (float*)&o0;
        float* P1 = (float*)&o1;
        #pragma unroll
        for (int k = 0; k < 4; ++k) {
            float e  = __expf(A[k] * dt);
            float ang = B[k] * dt;
            float cs = __cosf(ang), sn = __sinf(ang);
            float Vij = C[k] * (1.0f - e*e);
            float base = Vij * w1;
            float sc = -tau_a * __logf(base + EPSF);
            Q[k]  = __expf(sc) * IV[k];
            P0[k] = e * (cs*VR[k] - sn*VI[k]);
            P1[k] = e * (sn*VR[k] + cs*VI[k]);
        }
    }
    *(float4*)&Qout [j*DD + d0] = q4;
    *(float4*)&Z0out[j*DD + d0] = o0;
    *(float4*)&Z1out[j*DD + d0] = o1;
}

extern "C" void kernel_launch(void* const* d_in, const int* in_sizes, int n_in,
                              void* d_out, int out_size, void* d_ws, size_t ws_size,
                              hipStream_t stream) {
    const float* Zq    = (const float*)d_in[0];
    const float* Zk    = (const float*)d_in[1];
    const float* Zv    = (const float*)d_in[2];
    const float* t_all = (const float*)d_in[3];
    const float* Wq_w  = (const float*)d_in[4];
    const float* Wq_b  = (const float*)d_in[5];
    const float* Wk_w  = (const float*)d_in[6];
    const float* Wk_b  = (const float*)d_in[7];
    const float* l1    = (const float*)d_in[8];
    const float* lOm   = (const float*)d_in[9];
    const float* lGa   = (const float*)d_in[10];
    const float* nf    = (const float*)d_in[11];
    const float* tau   = (const float*)d_in[12];
    const float* nu    = (const float*)d_in[13];
    const float* etap  = (const float*)d_in[14];
    const float* lC    = (const float*)d_in[15];
    float* out = (float*)d_out;
    float* ws  = (float*)d_ws;

    afa_proj_kernel<<<2*TT, 128, 0, stream>>>(Zq, Zk, Wq_w, Wq_b, Wk_w, Wk_b,
                                              ws + W_QBUF, ws + W_KBUF);
    afa_tail_kernel<<<1, 64, 0, stream>>>(l1, t_all, lOm, lC, ws, out);
    afa_stats_kernel<<<TT*4, 256, 0, stream>>>(Zv, t_all, l1, lOm, lGa, nf,
                                               tau, nu, lC, ws);
    afa_combine_kernel<<<TT*DD/256, 256, 0, stream>>>(Zv, etap, ws, out);
    afa_write_kernel<<<TT*32, 256, 0, stream>>>(Zv, t_all, nf, tau, nu, ws, out);
}

// Round 5
// 64.480 us; speedup vs baseline: 2.1136x; 1.1177x over previous
//
#include <hip/hip_runtime.h>
#include <math.h>

#define TT 512
#define DD 64
#define EPSF 1e-5f

// output offsets (floats), concatenated in return order
#define O_EST  0                       // est_latent (1,2,512,64)
#define O_QIJ  (2*TT*DD)               // Q_ij (1,512,512,64)
#define O_ZHAT (O_QIJ + TT*TT*DD)      // Zhat (1,2,512,512,64)
#define O_LH   (O_ZHAT + 2*TT*TT*DD)   // lambda_h (2,64)
#define O_ME   (O_LH + 2*DD)           // mat_exp (1,2,64)

// ws layout (floats)
#define W_QBUF 0
#define W_KBUF (W_QBUF + 2*TT*DD)
#define W_SIJ  (W_KBUF + 2*TT*DD)          // [i*TT+j], causal only
#define W_S    (W_SIJ + TT*TT)             // [(i*4+ch)*64+d] partial sum (M=0 ref)
#define W_AR   (W_S + TT*4*DD)
#define W_AI   (W_AR + TT*4*DD)
#define W_IS   (W_AI + TT*4*DD)            // final 1/S per (i,d)
#define W_CA   (W_IS + TT*DD)              // a[d]
#define W_CB   (W_CA + DD)                 // bc[d]
#define W_CC   (W_CB + DD)                 // c1[d]
#define W_CG   (W_CC + DD)                 // lGa[d]

// ---------------- Q/K projection ----------------------------------------
__global__ __launch_bounds__(128) void afa_proj_kernel(
    const float* __restrict__ Zq, const float* __restrict__ Zk,
    const float* __restrict__ Wq_w, const float* __restrict__ Wq_b,
    const float* __restrict__ Wk_w, const float* __restrict__ Wk_b,
    float* __restrict__ Qbuf, float* __restrict__ Kbuf)
{
    int b = blockIdx.x;          // 0 .. 2*TT-1
    int c = b / TT, t = b % TT;
    __shared__ float zq[DD], zk[DD];
    int tid = threadIdx.x;
    if (tid < DD) zq[tid] = Zq[(c*TT + t)*DD + tid];
    else          zk[tid-DD] = Zk[(c*TT + t)*DD + (tid-DD)];
    __syncthreads();
    int o = tid & 63;
    const float* __restrict__ W  = (tid < 64) ? Wq_w : Wk_w;
    const float* __restrict__ bs = (tid < 64) ? Wq_b : Wk_b;
    const float* __restrict__ z  = (tid < 64) ? zq : zk;
    float* __restrict__ dst      = (tid < 64) ? Qbuf : Kbuf;
    float acc = bs[o];
    #pragma unroll
    for (int i4 = 0; i4 < 16; ++i4) {
        float4 w4 = *(const float4*)&W[o*DD + i4*4];
        acc = fmaf(z[i4*4+0], w4.x, acc);
        acc = fmaf(z[i4*4+1], w4.y, acc);
        acc = fmaf(z[i4*4+2], w4.z, acc);
        acc = fmaf(z[i4*4+3], w4.w, acc);
    }
    dst[(c*TT + t)*DD + o] = acc;
}

// ---------------- tiny outputs + per-d constant tables --------------------
__global__ __launch_bounds__(64) void afa_tail_kernel(
    const float* __restrict__ l1, const float* __restrict__ t_all,
    const float* __restrict__ lOm_, const float* __restrict__ lGa_,
    const float* __restrict__ lC,
    float* __restrict__ ws, float* __restrict__ out)
{
    int d = threadIdx.x;
    int h = d & 31;
    float a  = -fabsf(l1[h]);
    float bb = (d < 32) ? l1[32 + h] : -l1[32 + h];
    out[O_LH + d]      = a;
    out[O_LH + DD + d] = bb;
    float dT = t_all[TT] - t_all[TT-1];
    float me = __expf(a * dT);
    out[O_ME + d]      = me * __cosf(bb * dT);
    out[O_ME + DD + d] = me * __sinf(bb * dT);
    ws[W_CA + d] = a;
    ws[W_CB + d] = bb;
    ws[W_CC + d] = lC[d] * fabsf(lOm_[d]) / (-2.0f * a + EPSF);
    ws[W_CG + d] = fabsf(lGa_[d]) + EPSF;
}

// ---------------- stats + Zhat writer --------------------------------------
// block = (row i, contiguous j-chunk of 128). wave handles 4 j's at a time:
// lane = (jg:2)(dg:4), jg picks j, dg picks 4 consecutive d's (float4).
__global__ __launch_bounds__(256) void afa_stats_kernel(
    const float* __restrict__ Zv, const float* __restrict__ t_all,
    const float* __restrict__ nf,  const float* __restrict__ tau_,
    const float* __restrict__ nu_,
    float* __restrict__ ws, float* __restrict__ out)
{
    const float* Qbuf = ws + W_QBUF;
    const float* Kbuf = ws + W_KBUF;
    float* Sij = ws + W_SIJ;

    int bid = blockIdx.x;            // 2048 = 512 rows * 4 chunks
    int ch = bid & 3;
    int r  = bid >> 2;
    int i  = (r & 1) ? (TT - 1 - (r >> 1)) : (r >> 1);
    int tid = threadIdx.x;
    int w  = tid >> 6;
    int l  = tid & 63;
    int jg = l >> 4;                 // 0..3 : which j within the wave-iter
    int d0 = (l & 15) * 4;           // 0,4,...,60

    __shared__ float t_lds[TT];
    __shared__ float lsS[4][DD], lsR[4][DD], lsI[4][DD];
    for (int k = tid; k < TT; k += 256) t_lds[k] = t_all[k];

    float4 A4 = *(const float4*)&ws[W_CA + d0];
    float4 B4 = *(const float4*)&ws[W_CB + d0];
    float4 C4 = *(const float4*)&ws[W_CC + d0];
    float4 G4 = *(const float4*)&ws[W_CG + d0];
    const float* A = (const float*)&A4;
    const float* B = (const float*)&B4;
    const float* C = (const float*)&C4;
    const float* G = (const float*)&G4;
    float noise = fabsf(nf[0]);
    float tau_a = fabsf(tau_[0]);
    float nu_a  = fabsf(nu_[0]);
    float ti = t_all[i];
    float4 QR4 = *(const float4*)&Qbuf[i*DD + d0];
    float4 QI4 = *(const float4*)&Qbuf[TT*DD + i*DD + d0];
    const float* QR = (const float*)&QR4;
    const float* QI = (const float*)&QI4;

    float* __restrict__ Z0out = out + O_ZHAT + (size_t)i*TT*DD;
    float* __restrict__ Z1out = out + O_ZHAT + (size_t)TT*TT*DD + (size_t)i*TT*DD;

    __syncthreads();

    float s[4]  = {0.f,0.f,0.f,0.f};
    float ar[4] = {0.f,0.f,0.f,0.f};
    float ai[4] = {0.f,0.f,0.f,0.f};
    int lo = ch*128, hi = lo + 128;
    for (int j0 = lo + w*4; j0 < hi; j0 += 16) {
        int j = j0 + jg;
        if (j <= i) {
            float dt = ti - t_lds[j];
            float4 KR4 = *(const float4*)&Kbuf[j*DD + d0];
            float4 KI4 = *(const float4*)&Kbuf[TT*DD + j*DD + d0];
            float4 VR4 = *(const float4*)&Zv[j*DD + d0];
            float4 VI4 = *(const float4*)&Zv[TT*DD + j*DD + d0];
            const float* KR = (const float*)&KR4;
            const float* KI = (const float*)&KI4;
            const float* VR = (const float*)&VR4;
            const float* VI = (const float*)&VI4;
            float Vij[4], ZR[4], ZI[4];
            float mah = 0.f;
            #pragma unroll
            for (int k = 0; k < 4; ++k) {
                float e  = __expf(A[k] * dt);
                float ang = B[k] * dt;
                float cs = __cosf(ang), sn = __sinf(ang);
                float Rr = QR[k] - e * (cs*KR[k] - sn*KI[k]);
                float Ri = QI[k] - e * (sn*KR[k] + cs*KI[k]);
                Vij[k] = C[k] * (1.0f - e*e);
                mah += (Rr*Rr + Ri*Ri) / (Vij[k] + G[k]);
                ZR[k] = e * (cs*VR[k] - sn*VI[k]);
                ZI[k] = e * (sn*VR[k] + cs*VI[k]);
            }
            // reduce over the 16 d-group lanes (masks stay within group)
            mah += __shfl_xor(mah, 1);
            mah += __shfl_xor(mah, 2);
            mah += __shfl_xor(mah, 4);
            mah += __shfl_xor(mah, 8);
            if ((l & 15) == 0) Sij[i*TT + j] = mah;
            float w1 = noise + nu_a * mah;
            float4 z0, z1;
            float* Z0 = (float*)&z0;
            float* Z1 = (float*)&z1;
            #pragma unroll
            for (int k = 0; k < 4; ++k) {
                float base = Vij[k] * w1;
                float sc = -tau_a * __logf(base + EPSF);
                float p  = __expf(sc);            // fixed-ref M=0
                s[k]  += p;
                ar[k] = fmaf(p, ZR[k], ar[k]);
                ai[k] = fmaf(p, ZI[k], ai[k]);
                Z0[k] = ZR[k];
                Z1[k] = ZI[k];
            }
            *(float4*)&Z0out[(size_t)j*DD + d0] = z0;
            *(float4*)&Z1out[(size_t)j*DD + d0] = z1;
        } else {
            float4 z4 = make_float4(0.f,0.f,0.f,0.f);
            *(float4*)&Z0out[(size_t)j*DD + d0] = z4;
            *(float4*)&Z1out[(size_t)j*DD + d0] = z4;
        }
    }
    // combine the 4 jg groups (lanes l, l^16, l^32 have same d0)
    #pragma unroll
    for (int k = 0; k < 4; ++k) {
        s[k]  += __shfl_xor(s[k], 16);  s[k]  += __shfl_xor(s[k], 32);
        ar[k] += __shfl_xor(ar[k], 16); ar[k] += __shfl_xor(ar[k], 32);
        ai[k] += __shfl_xor(ai[k], 16); ai[k] += __shfl_xor(ai[k], 32);
    }
    if (jg == 0) {
        #pragma unroll
        for (int k = 0; k < 4; ++k) {
            lsS[w][d0+k] = s[k];
            lsR[w][d0+k] = ar[k];
            lsI[w][d0+k] = ai[k];
        }
    }
    __syncthreads();
    if (tid < 64) {
        float S = 0.f, AR = 0.f, AI = 0.f;
        #pragma unroll
        for (int ww = 0; ww < 4; ++ww) {
            S += lsS[ww][tid]; AR += lsR[ww][tid]; AI += lsI[ww][tid];
        }
        int o = (i*4 + ch)*DD + tid;
        ws[W_S  + o] = S;
        ws[W_AR + o] = AR;
        ws[W_AI + o] = AI;
    }
}

// ---------------- combine partials -> 1/S, est_latent ---------------------
__global__ __launch_bounds__(256) void afa_combine_kernel(
    const float* __restrict__ Zv, const float* __restrict__ etap,
    float* __restrict__ ws, float* __restrict__ out)
{
    int idx = blockIdx.x*256 + threadIdx.x;   // 0..32767 = i*64+d
    int i = idx >> 6, d = idx & 63;
    float S = 0.0f, AR = 0.0f, AI = 0.0f;
    #pragma unroll
    for (int c = 0; c < 4; ++c) {
        int o = (i*4 + c)*DD + d;
        S  += ws[W_S  + o];
        AR += ws[W_AR + o];
        AI += ws[W_AI + o];
    }
    float inv = 1.0f / S;
    ws[W_IS + idx] = inv;
    float eta = 1.0f / (1.0f + __expf(-etap[d]));
    float vr = Zv[i*DD + d], vi = Zv[TT*DD + i*DD + d];
    out[O_EST + idx]         = (1.0f - eta)*vr + eta*AR*inv;
    out[O_EST + TT*DD + idx] = (1.0f - eta)*vi + eta*AI*inv;
}

// ---------------- Q_ij writer (64 MB), no V / cos / sin -------------------
__global__ __launch_bounds__(256) void afa_qwrite_kernel(
    const float* __restrict__ t_all,
    const float* __restrict__ nf, const float* __restrict__ tau_,
    const float* __restrict__ nu_,
    const float* __restrict__ ws, float* __restrict__ out)
{
    int bid = blockIdx.x;            // 512*32 = 16384
    int i  = bid >> 5;
    int jt = bid & 31;               // 16 j's per block
    int tid = threadIdx.x;
    int jl = tid >> 4;               // 0..15
    int d0 = (tid & 15) * 4;
    int j  = jt*16 + jl;

    float* __restrict__ Qout = out + O_QIJ + (size_t)i*TT*DD;
    if (j > i) {
        *(float4*)&Qout[(size_t)j*DD + d0] = make_float4(0.f,0.f,0.f,0.f);
        return;
    }
    float noise = fabsf(nf[0]);
    float tau_a = fabsf(tau_[0]);
    float nu_a  = fabsf(nu_[0]);
    float4 A4   = *(const float4*)&ws[W_CA + d0];
    float4 C4   = *(const float4*)&ws[W_CC + d0];
    float4 IV4  = *(const float4*)&ws[W_IS + i*DD + d0];
    const float* A  = (const float*)&A4;
    const float* C  = (const float*)&C4;
    const float* IV = (const float*)&IV4;
    float dt = t_all[i] - t_all[j];
    float w1 = noise + nu_a * ws[W_SIJ + i*TT + j];
    float4 q4;
    float* Q = (float*)&q4;
    #pragma unroll
    for (int k = 0; k < 4; ++k) {
        float e2  = __expf(2.0f * A[k] * dt);
        float base = C[k] * (1.0f - e2) * w1;
        float sc = -tau_a * __logf(base + EPSF);
        Q[k] = __expf(sc) * IV[k];
    }
    *(float4*)&Qout[(size_t)j*DD + d0] = q4;
}

extern "C" void kernel_launch(void* const* d_in, const int* in_sizes, int n_in,
                              void* d_out, int out_size, void* d_ws, size_t ws_size,
                              hipStream_t stream) {
    const float* Zq    = (const float*)d_in[0];
    const float* Zk    = (const float*)d_in[1];
    const float* Zv    = (const float*)d_in[2];
    const float* t_all = (const float*)d_in[3];
    const float* Wq_w  = (const float*)d_in[4];
    const float* Wq_b  = (const float*)d_in[5];
    const float* Wk_w  = (const float*)d_in[6];
    const float* Wk_b  = (const float*)d_in[7];
    const float* l1    = (const float*)d_in[8];
    const float* lOm   = (const float*)d_in[9];
    const float* lGa   = (const float*)d_in[10];
    const float* nf    = (const float*)d_in[11];
    const float* tau   = (const float*)d_in[12];
    const float* nu    = (const float*)d_in[13];
    const float* etap  = (const float*)d_in[14];
    const float* lC    = (const float*)d_in[15];
    float* out = (float*)d_out;
    float* ws  = (float*)d_ws;

    afa_proj_kernel<<<2*TT, 128, 0, stream>>>(Zq, Zk, Wq_w, Wq_b, Wk_w, Wk_b,
                                              ws + W_QBUF, ws + W_KBUF);
    afa_tail_kernel<<<1, 64, 0, stream>>>(l1, t_all, lOm, lGa, lC, ws, out);
    afa_stats_kernel<<<TT*4, 256, 0, stream>>>(Zv, t_all, nf, tau, nu, ws, out);
    afa_combine_kernel<<<TT*DD/256, 256, 0, stream>>>(Zv, etap, ws, out);
    afa_qwrite_kernel<<<TT*32, 256, 0, stream>>>(t_all, nf, tau, nu, ws, out);
}

// Round 7
// 55.455 us; speedup vs baseline: 2.4575x; 1.1627x over previous
//
#include <hip/hip_runtime.h>
#include <math.h>

#define TT 512
#define DD 64
#define EPSF 1e-5f

typedef float f4 __attribute__((ext_vector_type(4)));   // native vector: OK for nontemporal builtins

// output offsets (floats), concatenated in return order
#define O_EST  0                       // est_latent (1,2,512,64)
#define O_QIJ  (2*TT*DD)               // Q_ij (1,512,512,64)
#define O_ZHAT (O_QIJ + TT*TT*DD)      // Zhat (1,2,512,512,64)
#define O_LH   (O_ZHAT + 2*TT*TT*DD)   // lambda_h (2,64)
#define O_ME   (O_LH + 2*DD)           // mat_exp (1,2,64)

// ws layout (floats)
#define W_QBUF 0
#define W_KBUF (W_QBUF + 2*TT*DD)
#define W_CA   (W_KBUF + 2*TT*DD)          // a[d]
#define W_CB   (W_CA + DD)                 // bc[d]
#define W_CC   (W_CB + DD)                 // c1[d]
#define W_CG   (W_CC + DD)                 // lGa[d]

// ---------------- Q/K projection ----------------------------------------
__global__ __launch_bounds__(128) void afa_proj_kernel(
    const float* __restrict__ Zq, const float* __restrict__ Zk,
    const float* __restrict__ Wq_w, const float* __restrict__ Wq_b,
    const float* __restrict__ Wk_w, const float* __restrict__ Wk_b,
    float* __restrict__ Qbuf, float* __restrict__ Kbuf)
{
    int b = blockIdx.x;          // 0 .. 2*TT-1
    int c = b / TT, t = b % TT;
    __shared__ float zq[DD], zk[DD];
    int tid = threadIdx.x;
    if (tid < DD) zq[tid] = Zq[(c*TT + t)*DD + tid];
    else          zk[tid-DD] = Zk[(c*TT + t)*DD + (tid-DD)];
    __syncthreads();
    int o = tid & 63;
    const float* __restrict__ W  = (tid < 64) ? Wq_w : Wk_w;
    const float* __restrict__ bs = (tid < 64) ? Wq_b : Wk_b;
    const float* __restrict__ z  = (tid < 64) ? zq : zk;
    float* __restrict__ dst      = (tid < 64) ? Qbuf : Kbuf;
    float acc = bs[o];
    #pragma unroll
    for (int i4 = 0; i4 < 16; ++i4) {
        f4 w4 = *(const f4*)&W[o*DD + i4*4];
        acc = fmaf(z[i4*4+0], w4.x, acc);
        acc = fmaf(z[i4*4+1], w4.y, acc);
        acc = fmaf(z[i4*4+2], w4.z, acc);
        acc = fmaf(z[i4*4+3], w4.w, acc);
    }
    dst[(c*TT + t)*DD + o] = acc;
}

// ---------------- tiny outputs + per-d constant tables --------------------
__global__ __launch_bounds__(64) void afa_tail_kernel(
    const float* __restrict__ l1, const float* __restrict__ t_all,
    const float* __restrict__ lOm_, const float* __restrict__ lGa_,
    const float* __restrict__ lC,
    float* __restrict__ ws, float* __restrict__ out)
{
    int d = threadIdx.x;
    int h = d & 31;
    float a  = -fabsf(l1[h]);
    float bb = (d < 32) ? l1[32 + h] : -l1[32 + h];
    out[O_LH + d]      = a;
    out[O_LH + DD + d] = bb;
    float dT = t_all[TT] - t_all[TT-1];
    float me = __expf(a * dT);
    out[O_ME + d]      = me * __cosf(bb * dT);
    out[O_ME + DD + d] = me * __sinf(bb * dT);
    ws[W_CA + d] = a;
    ws[W_CB + d] = bb;
    ws[W_CC + d] = lC[d] * fabsf(lOm_[d]) / (-2.0f * a + EPSF);
    ws[W_CG + d] = fabsf(lGa_[d]) + EPSF;
}

// ---------------- fused row kernel: Zhat + softmax + Q_ij + est_latent ----
// one block per row i, 512 threads = 8 waves.
// lane layout: jg = (lane>>4) picks j within wave-iter, d0 = (lane&15)*4.
__global__ __launch_bounds__(512) void afa_row_kernel(
    const float* __restrict__ Zv, const float* __restrict__ t_all,
    const float* __restrict__ nf,  const float* __restrict__ tau_,
    const float* __restrict__ nu_, const float* __restrict__ etap,
    const float* __restrict__ ws, float* __restrict__ out)
{
    const float* Qbuf = ws + W_QBUF;
    const float* Kbuf = ws + W_KBUF;

    int bid = blockIdx.x;
    int i = (bid & 1) ? (TT - 1 - (bid >> 1)) : (bid >> 1);
    int tid = threadIdx.x;
    int w  = tid >> 6;               // wave 0..7
    int l  = tid & 63;
    int jg = l >> 4;                 // 0..3
    int d0 = (l & 15) * 4;           // 0,4,...,60

    __shared__ float t_lds[TT];
    __shared__ float sij[TT];
    __shared__ float lsS[8][DD], lsR[8][DD], lsI[8][DD];
    __shared__ float invS[DD];

    t_lds[tid] = t_all[tid];         // 512 threads, 512 entries

    f4 A4 = *(const f4*)&ws[W_CA + d0];
    f4 B4 = *(const f4*)&ws[W_CB + d0];
    f4 C4 = *(const f4*)&ws[W_CC + d0];
    f4 G4 = *(const f4*)&ws[W_CG + d0];
    const float* A = (const float*)&A4;
    const float* B = (const float*)&B4;
    const float* C = (const float*)&C4;
    const float* G = (const float*)&G4;
    float noise = fabsf(nf[0]);
    float tau_a = fabsf(tau_[0]);
    float nu_a  = fabsf(nu_[0]);
    float ti = t_all[i];
    f4 QR4 = *(const f4*)&Qbuf[i*DD + d0];
    f4 QI4 = *(const f4*)&Qbuf[TT*DD + i*DD + d0];
    const float* QR = (const float*)&QR4;
    const float* QI = (const float*)&QI4;

    float* __restrict__ Qout  = out + O_QIJ  + (size_t)i*TT*DD;
    float* __restrict__ Z0out = out + O_ZHAT + (size_t)i*TT*DD;
    float* __restrict__ Z1out = out + O_ZHAT + (size_t)TT*TT*DD + (size_t)i*TT*DD;

    __syncthreads();

    // ---- Phase 1: mah -> sij (LDS), softmax partials, Zhat stream --------
    float s[4]  = {0.f,0.f,0.f,0.f};
    float ar[4] = {0.f,0.f,0.f,0.f};
    float ai[4] = {0.f,0.f,0.f,0.f};
    f4 zz4 = (f4)(0.0f);
    for (int j0 = w*4; j0 < TT; j0 += 32) {
        int j = j0 + jg;
        if (j <= i) {
            float dt = ti - t_lds[j];
            f4 KR4 = *(const f4*)&Kbuf[j*DD + d0];
            f4 KI4 = *(const f4*)&Kbuf[TT*DD + j*DD + d0];
            f4 VR4 = *(const f4*)&Zv[j*DD + d0];
            f4 VI4 = *(const f4*)&Zv[TT*DD + j*DD + d0];
            const float* KR = (const float*)&KR4;
            const float* KI = (const float*)&KI4;
            const float* VR = (const float*)&VR4;
            const float* VI = (const float*)&VI4;
            float Vij[4], ZR[4], ZI[4];
            float mah = 0.f;
            #pragma unroll
            for (int k = 0; k < 4; ++k) {
                float e  = __expf(A[k] * dt);
                float ang = B[k] * dt;
                float cs = __cosf(ang), sn = __sinf(ang);
                float Rr = QR[k] - e * (cs*KR[k] - sn*KI[k]);
                float Ri = QI[k] - e * (sn*KR[k] + cs*KI[k]);
                Vij[k] = C[k] * (1.0f - e*e);
                mah += (Rr*Rr + Ri*Ri) / (Vij[k] + G[k]);
                ZR[k] = e * (cs*VR[k] - sn*VI[k]);
                ZI[k] = e * (sn*VR[k] + cs*VI[k]);
            }
            // reduce over 16-lane d-group (masks stay in group; group-uniform branch)
            mah += __shfl_xor(mah, 1);
            mah += __shfl_xor(mah, 2);
            mah += __shfl_xor(mah, 4);
            mah += __shfl_xor(mah, 8);
            if ((l & 15) == 0) sij[j] = mah;
            float w1 = noise + nu_a * mah;
            f4 z0, z1;
            float* Z0 = (float*)&z0;
            float* Z1 = (float*)&z1;
            #pragma unroll
            for (int k = 0; k < 4; ++k) {
                float base = Vij[k] * w1;
                float sc = -tau_a * __logf(base + EPSF);
                float p  = __expf(sc);            // fixed-ref M=0 (scores bounded)
                s[k]  += p;
                ar[k] = fmaf(p, ZR[k], ar[k]);
                ai[k] = fmaf(p, ZI[k], ai[k]);
                Z0[k] = ZR[k];
                Z1[k] = ZI[k];
            }
            __builtin_nontemporal_store(z0, (f4*)&Z0out[(size_t)j*DD + d0]);
            __builtin_nontemporal_store(z1, (f4*)&Z1out[(size_t)j*DD + d0]);
        } else {
            __builtin_nontemporal_store(zz4, (f4*)&Z0out[(size_t)j*DD + d0]);
            __builtin_nontemporal_store(zz4, (f4*)&Z1out[(size_t)j*DD + d0]);
        }
    }
    // combine jg groups within the wave (lanes l, l^16, l^32 share d0)
    #pragma unroll
    for (int k = 0; k < 4; ++k) {
        s[k]  += __shfl_xor(s[k], 16);  s[k]  += __shfl_xor(s[k], 32);
        ar[k] += __shfl_xor(ar[k], 16); ar[k] += __shfl_xor(ar[k], 32);
        ai[k] += __shfl_xor(ai[k], 16); ai[k] += __shfl_xor(ai[k], 32);
    }
    if (jg == 0) {
        #pragma unroll
        for (int k = 0; k < 4; ++k) {
            lsS[w][d0+k] = s[k];
            lsR[w][d0+k] = ar[k];
            lsI[w][d0+k] = ai[k];
        }
    }
    __syncthreads();
    if (tid < 64) {
        float S = 0.f, AR = 0.f, AI = 0.f;
        #pragma unroll
        for (int ww = 0; ww < 8; ++ww) {
            S += lsS[ww][tid]; AR += lsR[ww][tid]; AI += lsI[ww][tid];
        }
        float inv = 1.0f / S;
        invS[tid] = inv;
        float eta = 1.0f / (1.0f + __expf(-etap[tid]));
        float vr = Zv[i*DD + tid], vi = Zv[TT*DD + i*DD + tid];
        out[O_EST + i*DD + tid]         = (1.0f - eta)*vr + eta*AR*inv;
        out[O_EST + TT*DD + i*DD + tid] = (1.0f - eta)*vi + eta*AI*inv;
    }
    __syncthreads();

    // ---- Phase 2: Q_ij stream from LDS sij ------------------------------
    int jl = tid >> 4;               // 0..31
    f4 inv4;
    inv4.x = invS[d0]; inv4.y = invS[d0+1]; inv4.z = invS[d0+2]; inv4.w = invS[d0+3];
    const float* IV = (const float*)&inv4;
    #pragma unroll 2
    for (int it = 0; it < 16; ++it) {
        int j = it*32 + jl;
        if (j <= i) {
            float dt = ti - t_lds[j];
            float w1 = noise + nu_a * sij[j];
            f4 q4;
            float* Q = (float*)&q4;
            #pragma unroll
            for (int k = 0; k < 4; ++k) {
                float e2  = __expf(2.0f * A[k] * dt);
                float base = C[k] * (1.0f - e2) * w1;
                float sc = -tau_a * __logf(base + EPSF);
                Q[k] = __expf(sc) * IV[k];
            }
            __builtin_nontemporal_store(q4, (f4*)&Qout[(size_t)j*DD + d0]);
        } else {
            __builtin_nontemporal_store(zz4, (f4*)&Qout[(size_t)j*DD + d0]);
        }
    }
}

extern "C" void kernel_launch(void* const* d_in, const int* in_sizes, int n_in,
                              void* d_out, int out_size, void* d_ws, size_t ws_size,
                              hipStream_t stream) {
    const float* Zq    = (const float*)d_in[0];
    const float* Zk    = (const float*)d_in[1];
    const float* Zv    = (const float*)d_in[2];
    const float* t_all = (const float*)d_in[3];
    const float* Wq_w  = (const float*)d_in[4];
    const float* Wq_b  = (const float*)d_in[5];
    const float* Wk_w  = (const float*)d_in[6];
    const float* Wk_b  = (const float*)d_in[7];
    const float* l1    = (const float*)d_in[8];
    const float* lOm   = (const float*)d_in[9];
    const float* lGa   = (const float*)d_in[10];
    const float* nf    = (const float*)d_in[11];
    const float* tau   = (const float*)d_in[12];
    const float* nu    = (const float*)d_in[13];
    const float* etap  = (const float*)d_in[14];
    const float* lC    = (const float*)d_in[15];
    float* out = (float*)d_out;
    float* ws  = (float*)d_ws;

    afa_proj_kernel<<<2*TT, 128, 0, stream>>>(Zq, Zk, Wq_w, Wq_b, Wk_w, Wk_b,
                                              ws + W_QBUF, ws + W_KBUF);
    afa_tail_kernel<<<1, 64, 0, stream>>>(l1, t_all, lOm, lGa, lC, ws, out);
    afa_row_kernel<<<TT, 512, 0, stream>>>(Zv, t_all, nf, tau, nu, etap, ws, out);
}